// Round 6
// baseline (206.267 us; speedup 1.0000x reference)
//
#include <hip/hip_runtime.h>
#include <math.h>

// Problem constants
#define BB   512   // batch
#define TT   256   // timesteps
#define CNNC 512   // channels
#define VV   37    // vocab
#define HH   8     // hidden
#define G4   32    // 4*H
#define CH   16    // scan chunk length (timesteps)
#define NCH  (TT / CH)      // 16 chunks
#define CHW  (CH * 256)     // floats per chunk of one 8-seq group (16 KB)

#define L2E 1.4426950408889634f

// native vector types for vector loads/stores (HIP float4 is a class type)
typedef float f4_t __attribute__((ext_vector_type(4)));
typedef float f2_t __attribute__((ext_vector_type(2)));

// DPP cross-lane mov: pure VALU latency. quad_perm 0xB1=xor1, 0x4E=xor2,
// 0x1B=xor3; 0x141=row_half_mirror (xor7); 0x140=row_mirror (xor15).
template <int CTRL>
__device__ __forceinline__ float dpp_f(float x) {
    int r = __builtin_amdgcn_update_dpp(0, __float_as_int(x), CTRL, 0xF, 0xF, true);
    return __int_as_float(r);
}

__device__ __forceinline__ float rcp_f(float x) { return __builtin_amdgcn_rcpf(x); }
__device__ __forceinline__ float exp2_f(float x) { return __builtin_amdgcn_exp2f(x); }

// packed dual-FP32 helpers (v_pk_fma_f32)
__device__ __forceinline__ f2_t fma2(f2_t a, f2_t b, f2_t c) {
    return __builtin_elementwise_fma(a, b, c);
}
__device__ __forceinline__ f2_t sp2(float x) { f2_t v = {x, x}; return v; }

// ---------------------------------------------------------------------------
// Kernel 1: avg-pool(features) @ W_in.T partial -> featp[quarter][B][V]
// (unchanged: BW-bound on the 51 MB feature read, at roofline)
// ---------------------------------------------------------------------------
__global__ __launch_bounds__(256) void k_feat(const float* __restrict__ features,
                                              const float* __restrict__ W_in,
                                              const float* __restrict__ b_in,
                                              float* __restrict__ featp) {
    __shared__ __align__(16) float raw[128 * 49];    // 25088 B
    __shared__ float pooled[128];
    const int b = blockIdx.x, qt = blockIdx.y, tid = threadIdx.x;
    const f4_t* src =
        (const f4_t*)(features + (size_t)b * CNNC * 49 + qt * (128 * 49));
    f4_t* dst = (f4_t*)raw;
    for (int i = tid; i < 128 * 49 / 4; i += 256)
        dst[i] = __builtin_nontemporal_load(&src[i]);
    __syncthreads();
    if (tid < 128) {
        const float* p = raw + tid * 49;
        float s = 0.f;
        #pragma unroll
        for (int i = 0; i < 49; ++i) s += p[i];
        pooled[tid] = s;
    }
    __syncthreads();
    const int v = tid >> 2, pp = tid & 3;
    if (v < VV) {
        const float* w = W_in + v * CNNC + qt * 128 + pp * 32;
        const float* q = pooled + pp * 32;
        float s = 0.f;
        #pragma unroll
        for (int i = 0; i < 32; ++i) s += q[i] * w[i];
        s += __shfl_xor(s, 1);
        s += __shfl_xor(s, 2);
        if (pp == 0)
            featp[(qt * BB + b) * VV + v] =
                s * (1.f / 49.f) + (qt == 0 ? b_in[v] : 0.f);
    }
}

// ---------------------------------------------------------------------------
// Kernel 2: xproj = -(x_t @ W_ih.T + b_ih + b_hh) * scale_g, pre-permuted.
// Word layout within a 4-seq half (128 words): word = ((gg&15)*4+s4)*2+(gg>>4)
// (lane's (A,B) pair adjacent -> one global_load_dwordx2 per lane per t).
// NEW: halves are packed two-per-256-word row so an 8-seq GROUP (for the
// dual-stream scan) is contiguous per t: group g = bg>>1, half = bg&1.
// ---------------------------------------------------------------------------
#define CAPS 1188   // per-seq caption stage stride (1184+4)
#define SOS  132    // out-stage stride per t (128+4)
__global__ __launch_bounds__(256) void k_xproj(const float* __restrict__ captions,
                                               const float* __restrict__ W_ih,
                                               const float* __restrict__ b_ih,
                                               const float* __restrict__ b_hh,
                                               const float* __restrict__ featp,
                                               float* __restrict__ xproj) {
    __shared__ float W[G4 * VV];                     // 4736 B
    __shared__ float bias[G4];
    __shared__ float cap[4 * CAPS];                  // 19008 B
    __shared__ __align__(16) float so[32 * SOS];     // 16896 B
    const int bg = blockIdx.x, tile = blockIdx.y;
    const int tid = threadIdx.x;
    for (int i = tid; i < G4 * VV; i += 256) W[i] = W_ih[i];
    if (tid < G4) bias[tid] = b_ih[tid] + b_hh[tid];

    // stage caption rows [start, start+32) for the block's 4 sequences
    const int t0 = tile * 32;
    const int start = (tile == 0) ? 0 : t0 - 1;
    for (int i = tid; i < 4 * 1184; i += 256) {
        const int s2 = i / 1184;                      // const-div -> mul/shift
        const int off = i - s2 * 1184;
        cap[s2 * CAPS + off] = __builtin_nontemporal_load(
            &captions[((size_t)(bg * 4 + s2) * TT + start) * VV + off]);
    }
    __syncthreads();

    const int tl = tid >> 3;             // 0..31 local t
    const int s  = (tid >> 1) & 3;       // seq within block
    const int r  = tid & 1;              // gate half (0: rows 0-15, 1: 16-31)
    const int b  = bg * 4 + s;

    float xr[VV];
    if (tile == 0 && tl == 0) {
        #pragma unroll
        for (int v = 0; v < VV; ++v)
            xr[v] = featp[b * VV + v] + featp[(BB + b) * VV + v] +
                    featp[(2 * BB + b) * VV + v] + featp[(3 * BB + b) * VV + v];
    } else {
        const int lr = (tile == 0) ? tl - 1 : tl;
        const float* x = &cap[s * CAPS + lr * VV];
        #pragma unroll
        for (int v = 0; v < VV; ++v) xr[v] = x[v];
    }

    const int g0 = r * 16;
    float acc[16];
    #pragma unroll
    for (int g = 0; g < 16; ++g) acc[g] = bias[g0 + g];
    #pragma unroll
    for (int v = 0; v < VV; ++v) {
        const float xv = xr[v];
        #pragma unroll
        for (int g = 0; g < 16; ++g) acc[g] += xv * W[(g0 + g) * VV + v];
    }
    #pragma unroll
    for (int g = 0; g < 16; ++g) {
        const int gg = g0 + g;
        const float sc = (gg >= 16 && gg < 24) ? (-2.f * L2E) : (-L2E);
        const int word = ((gg & 15) * 4 + s) * 2 + (gg >> 4);  // pair layout
        so[tl * SOS + word] = acc[g] * sc;
    }
    __syncthreads();

    // write the tile: 8-seq group rows are 256 words/t; this block = one half
    float* chunk =
        xproj + ((size_t)(bg >> 1) * TT + t0) * 256 + (bg & 1) * 128;
    for (int i = tid; i < 1024; i += 256) {
        const int t2 = i >> 5, rest = i & 31;
        f4_t val = *(const f4_t*)&so[t2 * SOS + rest * 4];
        *(f4_t*)&chunk[t2 * 256 + rest * 4] = val;
    }
}

// ---------------------------------------------------------------------------
// Kernel 3 (FUSED): dual-stream sequential scan + output softmax.
//   wave 0 (tid 0-63): 16 lanes/seq scan, TWO independent sequences per lane
//     group (stream P = group seqs 0-3, stream Q = seqs 4-7), interleaved in
//     the instruction stream. The scan is dependency-chain-latency bound
//     (~356 cyc/step, R2-R5 fits); the second stream's independent ops fill
//     the first's stall bubbles -> expect ~230 cyc per step-PAIR.
//     Per-stream structure is exactly R2/R4: pk dual-FP32 dots, v_rcp
//     sigmoids (R5's Newton reverted), zero-mem inner loop, chunk-end h flush.
//   waves 1-2 (tid 64-191): one chunk behind; 128 rows/slot, 1 row/lane:
//     37-logit dot + softmax + scalar stores (R2-proven form).
// Sync: raw s_barrier + lgkmcnt(0) only (no vmcnt drain).
// ---------------------------------------------------------------------------
#define TSTR 12                 // hst per-t dword stride (8 data + 4 pad)
#define SSTR (CH * TSTR + 4)    // 196: per (buffer,seq) stride

#define STEPX(cur, tl, h, c, hsv) do {                                      \
    const f2_t p2 = cur[tl];                                                \
    const float ha0 = h;                                                    \
    const float ha1 = dpp_f<0x4E>(h);                                       \
    const float ha3 = dpp_f<0x141>(h);                                      \
    const float ha2 = dpp_f<0x4E>(ha3);                                     \
    const float ha7 = dpp_f<0x140>(h);                                      \
    const float ha4 = dpp_f<0x141>(ha7);                                    \
    const float ha5 = dpp_f<0x4E>(ha4);                                     \
    const float ha6 = dpp_f<0x1B>(ha7);                                     \
    f2_t acc0 = fma2(w2[0], sp2(ha0), p2);                                  \
    acc0 = fma2(w2[1], sp2(ha1), acc0);                                     \
    acc0 = fma2(w2[2], sp2(ha2), acc0);                                     \
    acc0 = fma2(w2[3], sp2(ha3), acc0);                                     \
    f2_t acc1 = w2[4] * sp2(ha4);                                           \
    acc1 = fma2(w2[5], sp2(ha5), acc1);                                     \
    acc1 = fma2(w2[6], sp2(ha6), acc1);                                     \
    acc1 = fma2(w2[7], sp2(ha7), acc1);                                     \
    const f2_t np2 = acc0 + acc1;                                           \
    const float eA = rcp_f(1.f + exp2_f(np2.x));  /* r=0: i ; r=1: f */     \
    const float uB = rcp_f(1.f + exp2_f(np2.y));  /* r=0: raw g ; r=1: o */ \
    const float gg = fmaf(-4.f * L2E, uB, 2.f * L2E); /* -2L2E*tanh(g) */   \
    const float myU = r ? eA : eA * gg;           /* r=0: -2L2E*i*g; r=1: f */\
    const float otU = dpp_f<0xB1>(myU);                                     \
    const float fg  = r ? myU : otU;                                        \
    const float igg = r ? otU : myU;                                        \
    const float ogx = dpp_f<0xB1>(uB);                                      \
    const float og  = r ? uB : ogx;                                         \
    c = fmaf(fg, c, igg);                         /* c holds -2L2E*c_true */\
    const float rv = rcp_f(1.f + exp2_f(c));                                \
    h = fmaf(og + og, rv, -og);                   /* og*(2rv-1) */          \
    hsv[tl] = h;                                                            \
} while (0)

#define CHUNK2(curP, curQ, nxtP, nxtQ, it, pbuf) do {                       \
    if ((it) + 1 < NCH) {                                                   \
        const f2_t* sp = (const f2_t*)xp + (size_t)((it) + 1) * (CHW / 2) + roff1; \
        _Pragma("unroll")                                                   \
        for (int tl = 0; tl < CH; ++tl) {                                   \
            nxtP[tl] = sp[tl * 128];                                        \
            nxtQ[tl] = sp[tl * 128 + 64];                                   \
        }                                                                   \
        __builtin_amdgcn_sched_barrier(0);                                  \
    }                                                                       \
    _Pragma("unroll")                                                       \
    for (int tl = 0; tl < CH; ++tl) {                                       \
        STEPX(curP, tl, hP, cP, hsvP);                                      \
        STEPX(curQ, tl, hQ, cQ, hsvQ);                                      \
    }                                                                       \
    if (r == 0) {                                                           \
        float* hbP = &hst[((pbuf) * 8 + s4) * SSTR + j];                    \
        float* hbQ = &hst[((pbuf) * 8 + 4 + s4) * SSTR + j];                \
        _Pragma("unroll")                                                   \
        for (int i = 0; i < CH; ++i) {                                      \
            hbP[i * TSTR] = hsvP[i];                                        \
            hbQ[i * TSTR] = hsvQ[i];                                        \
        }                                                                   \
    }                                                                       \
} while (0)

#define EMIT(pk) do {                                                       \
    const int row = (wv - 1) * 64 + lane;        /* 0..127 */               \
    const int os = row >> 4, otl = row & 15;                                \
    const float* hp = &hst[(((pk) & 1) * 8 + os) * SSTR + otl * TSTR];      \
    const f4_t h0 = *(const f4_t*)hp;                                       \
    const f4_t h1 = *(const f4_t*)(hp + 4);                                 \
    const f4_t* W4 = (const f4_t*)Wo;                                       \
    float z[VV];                                                            \
    float m = -1e30f;                                                       \
    _Pragma("unroll")                                                       \
    for (int v = 0; v < VV; ++v) {                                          \
        const f4_t w0 = W4[v * 2], w1 = W4[v * 2 + 1];                      \
        float sv = bo[v];                                                   \
        sv = fmaf(h0.x, w0.x, sv); sv = fmaf(h0.y, w0.y, sv);               \
        sv = fmaf(h0.z, w0.z, sv); sv = fmaf(h0.w, w0.w, sv);               \
        sv = fmaf(h1.x, w1.x, sv); sv = fmaf(h1.y, w1.y, sv);               \
        sv = fmaf(h1.z, w1.z, sv); sv = fmaf(h1.w, w1.w, sv);               \
        z[v] = sv;                                                          \
        m = fmaxf(m, sv);                                                   \
    }                                                                       \
    float sum = 0.f;                                                        \
    _Pragma("unroll")                                                       \
    for (int v = 0; v < VV; ++v) {                                          \
        z[v] = exp2_f((z[v] - m) * L2E);                                    \
        sum += z[v];                                                        \
    }                                                                       \
    const float rs = rcp_f(sum);                                            \
    const int ob = bg * 8 + os;                                             \
    const int ot = (pk) * CH + otl;                                         \
    float* op = out + ((size_t)ob * TT + ot) * VV;                          \
    _Pragma("unroll")                                                       \
    for (int v = 0; v < VV; ++v) op[v] = z[v] * rs;                         \
} while (0)

__global__ __launch_bounds__(192) void k_lstm(const float* __restrict__ W_hh,
                                              const float* __restrict__ xproj,
                                              const float* __restrict__ W_out,
                                              const float* __restrict__ b_out,
                                              float* __restrict__ out) {
    __shared__ __align__(16) float hst[2 * 8 * SSTR];   // 12544 B
    __shared__ __align__(16) float Wo[VV * HH];
    __shared__ float bo[VV];

    const int tid  = threadIdx.x;
    const int wv   = tid >> 6;        // 0: scan; 1,2: output
    const int lane = tid & 63;
    const int bg   = blockIdx.x;      // 0..63 (8-seq groups)
    const float* xp = xproj + (size_t)bg * (TT * 256);

    // scan-wave lane decode
    const int s4 = lane >> 4;
    const int q  = lane & 15;
    const int j  = q >> 1;
    const int r  = q & 1;
    const int rowA  = r * 8 + j;                 // i or f row
    const int roff1 = rowA * 4 + s4;             // f2-offset of (A,B) pair

    f2_t cPA[CH], cPB[CH], cQA[CH], cQB[CH];
    float hsvP[CH], hsvQ[CH];
    f2_t w2[HH];                                 // packed (wA, wB), shared P/Q

    if (wv == 0) {
        const int rowB = 16 + rowA;              // g or o row
        const float scA = -L2E;
        const float scB = r ? -L2E : (-2.f * L2E);
        #pragma unroll
        for (int m = 0; m < HH; ++m) {
            f2_t wp = {scA * W_hh[rowA * HH + (j ^ m)],
                       scB * W_hh[rowB * HH + (j ^ m)]};
            w2[m] = wp;
        }
        // prefetch chunk 0 for both streams
        const f2_t* sp = (const f2_t*)xp + roff1;
        #pragma unroll
        for (int tl = 0; tl < CH; ++tl) {
            cPA[tl] = sp[tl * 128];
            cQA[tl] = sp[tl * 128 + 64];
        }
    } else {
        const int l2 = tid - 64;                 // 0..127
        for (int i = l2; i < VV * HH; i += 128) Wo[i] = W_out[i];
        if (l2 < VV) bo[l2] = b_out[l2];
    }

    float hP = 0.f, cP = 0.f, hQ = 0.f, cQ = 0.f;

    // 18 slots (9 outer x 2), slots 0..16 active: wave0 computes chunk `it`
    // (it<16), waves 1-2 emit chunk `it-1` (1<=it<=16). Uniform barriers.
    for (int ou = 0; ou < 9; ++ou) {
        {
            const int it = ou * 2;
            if (wv == 0) {
                if (it < NCH) CHUNK2(cPA, cQA, cPB, cQB, it, 0);
            } else if (it >= 1 && it <= NCH) {
                EMIT(it - 1);
            }
            asm volatile("s_waitcnt lgkmcnt(0)" ::: "memory");
            __builtin_amdgcn_s_barrier();
            __builtin_amdgcn_sched_barrier(0);
        }
        {
            const int it = ou * 2 + 1;
            if (it <= NCH) {
                if (wv == 0) {
                    if (it < NCH) CHUNK2(cPB, cQB, cPA, cQA, it, 1);
                } else {
                    EMIT(it - 1);
                }
                asm volatile("s_waitcnt lgkmcnt(0)" ::: "memory");
                __builtin_amdgcn_s_barrier();
                __builtin_amdgcn_sched_barrier(0);
            }
        }
    }
}

// ---------------------------------------------------------------------------
// Workspace (floats): featp@0 (4*512*37=75,776) | xproj@81920 (4,194,304)
// ---------------------------------------------------------------------------
extern "C" void kernel_launch(void* const* d_in, const int* in_sizes, int n_in,
                              void* d_out, int out_size, void* d_ws, size_t ws_size,
                              hipStream_t stream) {
    const float* features = (const float*)d_in[0];
    const float* captions = (const float*)d_in[1];
    const float* W_in     = (const float*)d_in[2];
    const float* b_in     = (const float*)d_in[3];
    const float* W_ih     = (const float*)d_in[4];
    const float* W_hh     = (const float*)d_in[5];
    const float* b_ih     = (const float*)d_in[6];
    const float* b_hh     = (const float*)d_in[7];
    const float* W_out    = (const float*)d_in[8];
    const float* b_out    = (const float*)d_in[9];
    float* out = (float*)d_out;

    float* ws    = (float*)d_ws;
    float* featp = ws;
    float* xproj = ws + 81920;

    k_feat <<<dim3(BB, 4),  256, 0, stream>>>(features, W_in, b_in, featp);
    k_xproj<<<dim3(128, 8), 256, 0, stream>>>(captions, W_ih, b_ih, b_hh, featp, xproj);
    k_lstm <<<64,           192, 0, stream>>>(W_hh, xproj, W_out, b_out, out);
}

// Round 7
// 174.451 us; speedup vs baseline: 1.1824x; 1.1824x over previous
//
#include <hip/hip_runtime.h>
#include <math.h>

// Problem constants
#define BB   512   // batch
#define TT   256   // timesteps
#define CNNC 512   // channels
#define VV   37    // vocab
#define HH   8     // hidden
#define G4   32    // 4*H
#define CH   16    // scan chunk length (timesteps)
#define NCH  (TT / CH)      // 16 chunks

#define L2E 1.4426950408889634f

// native vector types for vector loads/stores (HIP float4 is a class type)
typedef float f4_t __attribute__((ext_vector_type(4)));
typedef float f2_t __attribute__((ext_vector_type(2)));

// DPP cross-lane mov: pure VALU latency. quad_perm 0xB1=xor1, 0x4E=xor2,
// 0x1B=xor3; 0x141=row_half_mirror (xor7); 0x140=row_mirror (xor15).
template <int CTRL>
__device__ __forceinline__ float dpp_f(float x) {
    int r = __builtin_amdgcn_update_dpp(0, __float_as_int(x), CTRL, 0xF, 0xF, true);
    return __int_as_float(r);
}

__device__ __forceinline__ float rcp_f(float x) { return __builtin_amdgcn_rcpf(x); }
__device__ __forceinline__ float exp2_f(float x) { return __builtin_amdgcn_exp2f(x); }

// packed dual-FP32 helpers (v_pk_fma_f32)
__device__ __forceinline__ f2_t fma2(f2_t a, f2_t b, f2_t c) {
    return __builtin_elementwise_fma(a, b, c);
}
__device__ __forceinline__ f2_t sp2(float x) { f2_t v = {x, x}; return v; }

// ---------------------------------------------------------------------------
// Kernel 1: avg-pool(features) @ W_in.T partial -> featp[quarter][B][V]
// (unchanged: BW-bound on the 51 MB feature read, at roofline)
// ---------------------------------------------------------------------------
__global__ __launch_bounds__(256) void k_feat(const float* __restrict__ features,
                                              const float* __restrict__ W_in,
                                              const float* __restrict__ b_in,
                                              float* __restrict__ featp) {
    __shared__ __align__(16) float raw[128 * 49];    // 25088 B
    __shared__ float pooled[128];
    const int b = blockIdx.x, qt = blockIdx.y, tid = threadIdx.x;
    const f4_t* src =
        (const f4_t*)(features + (size_t)b * CNNC * 49 + qt * (128 * 49));
    f4_t* dst = (f4_t*)raw;
    for (int i = tid; i < 128 * 49 / 4; i += 256)
        dst[i] = __builtin_nontemporal_load(&src[i]);
    __syncthreads();
    if (tid < 128) {
        const float* p = raw + tid * 49;
        float s = 0.f;
        #pragma unroll
        for (int i = 0; i < 49; ++i) s += p[i];
        pooled[tid] = s;
    }
    __syncthreads();
    const int v = tid >> 2, pp = tid & 3;
    if (v < VV) {
        const float* w = W_in + v * CNNC + qt * 128 + pp * 32;
        const float* q = pooled + pp * 32;
        float s = 0.f;
        #pragma unroll
        for (int i = 0; i < 32; ++i) s += q[i] * w[i];
        s += __shfl_xor(s, 1);
        s += __shfl_xor(s, 2);
        if (pp == 0)
            featp[(qt * BB + b) * VV + v] =
                s * (1.f / 49.f) + (qt == 0 ? b_in[v] : 0.f);
    }
}

// ---------------------------------------------------------------------------
// Kernel 2 (FULLY FUSED): xproj-producer + scan + output softmax. 4 waves.
//   wave 0 (tid 0-63):   R2-exact scan (16 lanes/seq, pk dual-FP32 dots,
//                        v_rcp sigmoids). Reads its (A,B) pre-activation pair
//                        per step from the LDS ring (one ds_read_b64/lane/t).
//   wave 1 (tid 64-127): EMIT, one chunk behind scan (R2-proven form).
//   waves 2-3 (tid 128-255): PRODUCER: compute chunk it+1's x-projection
//                        -(x @ W_ih.T + b_ih + b_hh)*scale into the LDS ring
//                        (one chunk ahead of the scan). W_ih in LDS; captions
//                        read directly from global (cached; each row hit by
//                        2 adjacent lanes). k_xproj kernel DELETED: saves its
//                        ~6 us + launch gap + 16 MB HBM round trip, hidden
//                        entirely inside the latency-bound scan slot
//                        (producer ~1.3K cyc vs scan slot ~6K cyc).
// Ring rows padded to 132 words: producer's 16 scalar ds_writes per thread
// land in 32 distinct banks (4*ptl + 2*ps + pr covers 0..31) -> conflict-free.
// Sync: raw s_barrier + lgkmcnt(0) per slot (covers ds_write->ds_read).
// ---------------------------------------------------------------------------
#define TSTR 12                 // hst per-t dword stride (8 data + 4 pad)
#define SSTR (CH * TSTR + 4)    // 196: per (buffer,seq) stride
#define RSTR 132                // ring row stride (128 data + 4 pad)
#define RING_T (CH * RSTR)      // 2112 floats per chunk tile

#define BAR() do {                                                          \
    asm volatile("s_waitcnt lgkmcnt(0)" ::: "memory");                      \
    __builtin_amdgcn_s_barrier();                                           \
    __builtin_amdgcn_sched_barrier(0);                                      \
} while (0)

#define STEP(p2) do {                                                       \
    const float ha0 = h;                                                    \
    const float ha1 = dpp_f<0x4E>(h);                                       \
    const float ha3 = dpp_f<0x141>(h);                                      \
    const float ha2 = dpp_f<0x4E>(ha3);                                     \
    const float ha7 = dpp_f<0x140>(h);                                      \
    const float ha4 = dpp_f<0x141>(ha7);                                    \
    const float ha5 = dpp_f<0x4E>(ha4);                                     \
    const float ha6 = dpp_f<0x1B>(ha7);                                     \
    f2_t acc0 = fma2(w2[0], sp2(ha0), p2);                                  \
    acc0 = fma2(w2[1], sp2(ha1), acc0);                                     \
    acc0 = fma2(w2[2], sp2(ha2), acc0);                                     \
    acc0 = fma2(w2[3], sp2(ha3), acc0);                                     \
    f2_t acc1 = w2[4] * sp2(ha4);                                           \
    acc1 = fma2(w2[5], sp2(ha5), acc1);                                     \
    acc1 = fma2(w2[6], sp2(ha6), acc1);                                     \
    acc1 = fma2(w2[7], sp2(ha7), acc1);                                     \
    const f2_t np2 = acc0 + acc1;                                           \
    const float eA = rcp_f(1.f + exp2_f(np2.x));  /* r=0: i ; r=1: f */     \
    const float uB = rcp_f(1.f + exp2_f(np2.y));  /* r=0: raw g ; r=1: o */ \
    const float gg = fmaf(-4.f * L2E, uB, 2.f * L2E); /* -2L2E*tanh(g) */   \
    const float myU = r ? eA : eA * gg;           /* r=0: -2L2E*i*g; r=1: f */\
    const float otU = dpp_f<0xB1>(myU);                                     \
    const float fg  = r ? myU : otU;                                        \
    const float igg = r ? otU : myU;                                        \
    const float ogx = dpp_f<0xB1>(uB);                                      \
    const float og  = r ? uB : ogx;                                         \
    c = fmaf(fg, c, igg);                         /* c holds -2L2E*c_true */\
    const float rv = rcp_f(1.f + exp2_f(c));                                \
    h = fmaf(og + og, rv, -og);                   /* og*(2rv-1) */          \
} while (0)

#define SCHUNK(it) do {                                                     \
    const float* base = &ring[((it) % 3) * RING_T] + roff2w;                \
    float hsv[CH];                                                          \
    _Pragma("unroll")                                                       \
    for (int tl = 0; tl < CH; ++tl) {                                       \
        const f2_t p2 = *(const f2_t*)&base[tl * RSTR];                     \
        STEP(p2);                                                           \
        hsv[tl] = h;                                                        \
    }                                                                       \
    if (r == 0) {                                                           \
        float* hb = &hst[(((it) & 1) * 4 + s4) * SSTR + j];                 \
        _Pragma("unroll")                                                   \
        for (int i = 0; i < CH; ++i) hb[i * TSTR] = hsv[i];                 \
    }                                                                       \
} while (0)

#define PRODUCE_BODY(pk)                                                    \
    float acc[16];                                                          \
    _Pragma("unroll")                                                       \
    for (int g = 0; g < 16; ++g) acc[g] = bs[g];                            \
    _Pragma("unroll")                                                       \
    for (int v = 0; v < VV; ++v) {                                          \
        const float xv = xr[v];                                             \
        _Pragma("unroll")                                                   \
        for (int g = 0; g < 16; ++g) acc[g] += xv * Wih[(g0 + g) * VV + v]; \
    }                                                                       \
    float* dst = &ring[((pk) % 3) * RING_T + ptl * RSTR];                   \
    _Pragma("unroll")                                                       \
    for (int g = 0; g < 16; ++g) {                                          \
        const int gg = g0 + g;                                              \
        const float sc = (gg >= 16 && gg < 24) ? (-2.f * L2E) : (-L2E);     \
        dst[((gg & 15) * 4 + ps) * 2 + (gg >> 4)] = acc[g] * sc;            \
    }

#define PRODUCE(pk) do {          /* pk >= 1: pure caption path */          \
    const int t = (pk) * CH + ptl;                                          \
    const float* x = captions + ((size_t)pb * TT + (t - 1)) * VV;           \
    float xr[VV];                                                           \
    _Pragma("unroll")                                                       \
    for (int v = 0; v < VV; ++v) xr[v] = x[v];                              \
    PRODUCE_BODY(pk)                                                        \
} while (0)

#define EMIT(pk) do {                                                       \
    const int os = lane >> 4, otl = lane & 15;                              \
    const float* hp = &hst[(((pk) & 1) * 4 + os) * SSTR + otl * TSTR];      \
    const f4_t h0 = *(const f4_t*)hp;                                       \
    const f4_t h1 = *(const f4_t*)(hp + 4);                                 \
    const f4_t* W4 = (const f4_t*)Wo;                                       \
    float z[VV];                                                            \
    float m = -1e30f;                                                       \
    _Pragma("unroll")                                                       \
    for (int v = 0; v < VV; ++v) {                                          \
        const f4_t w0 = W4[v * 2], w1 = W4[v * 2 + 1];                      \
        float sv = bo[v];                                                   \
        sv = fmaf(h0.x, w0.x, sv); sv = fmaf(h0.y, w0.y, sv);               \
        sv = fmaf(h0.z, w0.z, sv); sv = fmaf(h0.w, w0.w, sv);               \
        sv = fmaf(h1.x, w1.x, sv); sv = fmaf(h1.y, w1.y, sv);               \
        sv = fmaf(h1.z, w1.z, sv); sv = fmaf(h1.w, w1.w, sv);               \
        z[v] = sv;                                                          \
        m = fmaxf(m, sv);                                                   \
    }                                                                       \
    float sum = 0.f;                                                        \
    _Pragma("unroll")                                                       \
    for (int v = 0; v < VV; ++v) {                                          \
        z[v] = exp2_f((z[v] - m) * L2E);                                    \
        sum += z[v];                                                        \
    }                                                                       \
    const float rs = rcp_f(sum);                                            \
    const int ob = bg * 4 + os;                                             \
    const int ot = (pk) * CH + otl;                                         \
    float* op = out + ((size_t)ob * TT + ot) * VV;                          \
    _Pragma("unroll")                                                       \
    for (int v = 0; v < VV; ++v) op[v] = z[v] * rs;                         \
} while (0)

__global__ __launch_bounds__(256) void k_lstm(const float* __restrict__ W_hh,
                                              const float* __restrict__ captions,
                                              const float* __restrict__ W_ih,
                                              const float* __restrict__ b_ih,
                                              const float* __restrict__ b_hh,
                                              const float* __restrict__ featp,
                                              const float* __restrict__ W_out,
                                              const float* __restrict__ b_out,
                                              float* __restrict__ out) {
    __shared__ __align__(16) float ring[3 * RING_T];    // 25344 B
    __shared__ __align__(16) float hst[2 * 4 * SSTR];   // 6272 B
    __shared__ __align__(16) float Wih[G4 * VV];        // 4736 B
    __shared__ __align__(16) float Wo[VV * HH];         // 1184 B
    __shared__ float bo[VV];

    const int tid  = threadIdx.x;
    const int wv   = tid >> 6;        // 0: scan; 1: emit; 2,3: produce
    const int lane = tid & 63;
    const int bg   = blockIdx.x;      // 0..127 (4-seq groups)

    // scan-wave lane decode
    const int s4 = lane >> 4;
    const int q  = lane & 15;
    const int j  = q >> 1;
    const int r  = q & 1;
    const int rowA   = r * 8 + j;                // i or f row
    const int roff2w = (rowA * 4 + s4) * 2;      // word offset of (A,B) pair

    // producer lane decode (waves 2-3 jointly: p = 0..127)
    const int p   = tid & 127;
    const int ptl = p >> 3;            // 0..15 local t
    const int ps  = (p >> 1) & 3;      // seq within block
    const int pr  = p & 1;             // gate half
    const int g0  = pr * 16;
    const int pb  = bg * 4 + ps;

    f2_t w2[HH];                       // scan: packed (wA, wB)
    float bs[16];                      // producer: bias registers

    if (wv == 0) {
        const int rowB = 16 + rowA;
        const float scA = -L2E;
        const float scB = r ? -L2E : (-2.f * L2E);
        #pragma unroll
        for (int m = 0; m < HH; ++m) {
            f2_t wp = {scA * W_hh[rowA * HH + (j ^ m)],
                       scB * W_hh[rowB * HH + (j ^ m)]};
            w2[m] = wp;
        }
    } else if (wv == 1) {
        for (int i = lane; i < VV * HH; i += 64) Wo[i] = W_out[i];
        if (lane < VV) bo[lane] = b_out[lane];
    } else {
        for (int i = p; i < G4 * VV; i += 128) Wih[i] = W_ih[i];
        #pragma unroll
        for (int g = 0; g < 16; ++g) bs[g] = b_ih[g0 + g] + b_hh[g0 + g];
    }
    BAR();   // Wih/Wo staged

    // prologue: produce chunk 0 (t=0 row comes from featp partial sums)
    if (wv >= 2) {
        float xr[VV];
        if (ptl == 0) {
            #pragma unroll
            for (int v = 0; v < VV; ++v)
                xr[v] = featp[pb * VV + v] + featp[(BB + pb) * VV + v] +
                        featp[(2 * BB + pb) * VV + v] +
                        featp[(3 * BB + pb) * VV + v];
        } else {
            const float* x = captions + ((size_t)pb * TT + (ptl - 1)) * VV;
            #pragma unroll
            for (int v = 0; v < VV; ++v) xr[v] = x[v];
        }
        PRODUCE_BODY(0)
    }
    BAR();   // chunk 0 ready

    float h = 0.f, c = 0.f;

    // slots 0..16: wave0 scans chunk it (it<16); wave1 emits it-1 (it>=1);
    // waves 2-3 produce chunk it+1 (it<15). Ring: read it%3, write (it+1)%3.
    for (int it = 0; it < NCH + 1; ++it) {
        if (wv == 0) {
            if (it < NCH) SCHUNK(it);
        } else if (wv == 1) {
            if (it >= 1) EMIT(it - 1);
        } else {
            if (it < NCH - 1) PRODUCE(it + 1);
        }
        BAR();
    }
}

// ---------------------------------------------------------------------------
// Workspace (floats): featp@0 (4*512*37=75,776). xproj eliminated.
// ---------------------------------------------------------------------------
extern "C" void kernel_launch(void* const* d_in, const int* in_sizes, int n_in,
                              void* d_out, int out_size, void* d_ws, size_t ws_size,
                              hipStream_t stream) {
    const float* features = (const float*)d_in[0];
    const float* captions = (const float*)d_in[1];
    const float* W_in     = (const float*)d_in[2];
    const float* b_in     = (const float*)d_in[3];
    const float* W_ih     = (const float*)d_in[4];
    const float* W_hh     = (const float*)d_in[5];
    const float* b_ih     = (const float*)d_in[6];
    const float* b_hh     = (const float*)d_in[7];
    const float* W_out    = (const float*)d_in[8];
    const float* b_out    = (const float*)d_in[9];
    float* out = (float*)d_out;

    float* featp = (float*)d_ws;

    k_feat<<<dim3(BB, 4), 256, 0, stream>>>(features, W_in, b_in, featp);
    k_lstm<<<128,         256, 0, stream>>>(W_hh, captions, W_ih, b_ih, b_hh,
                                            featp, W_out, b_out, out);
}

// Round 8
// 163.889 us; speedup vs baseline: 1.2586x; 1.0645x over previous
//
#include <hip/hip_runtime.h>
#include <math.h>

// Problem constants
#define BB   512   // batch
#define TT   256   // timesteps
#define CNNC 512   // channels
#define VV   37    // vocab
#define HH   8     // hidden
#define G4   32    // 4*H
#define CH   16    // scan chunk length (timesteps)
#define NCH  (TT / CH)      // 16 chunks

#define L2E 1.4426950408889634f

// native vector types for vector loads/stores (HIP float4 is a class type)
typedef float f4_t __attribute__((ext_vector_type(4)));
typedef float f2_t __attribute__((ext_vector_type(2)));

// DPP cross-lane mov: pure VALU latency. quad_perm 0xB1=xor1, 0x4E=xor2,
// 0x1B=xor3; 0x141=row_half_mirror (xor7); 0x140=row_mirror (xor15).
template <int CTRL>
__device__ __forceinline__ float dpp_f(float x) {
    int r = __builtin_amdgcn_update_dpp(0, __float_as_int(x), CTRL, 0xF, 0xF, true);
    return __int_as_float(r);
}

__device__ __forceinline__ float rcp_f(float x) { return __builtin_amdgcn_rcpf(x); }
__device__ __forceinline__ float exp2_f(float x) { return __builtin_amdgcn_exp2f(x); }

// packed dual-FP32 helpers (v_pk_fma_f32)
__device__ __forceinline__ f2_t fma2(f2_t a, f2_t b, f2_t c) {
    return __builtin_elementwise_fma(a, b, c);
}
__device__ __forceinline__ f2_t sp2(float x) { f2_t v = {x, x}; return v; }

// ---------------------------------------------------------------------------
// Kernel 1: avg-pool(features) @ W_in.T partial -> featp[quarter][B][V]
// (unchanged: BW-bound on the 51 MB feature read, at roofline)
// ---------------------------------------------------------------------------
__global__ __launch_bounds__(256) void k_feat(const float* __restrict__ features,
                                              const float* __restrict__ W_in,
                                              const float* __restrict__ b_in,
                                              float* __restrict__ featp) {
    __shared__ __align__(16) float raw[128 * 49];    // 25088 B
    __shared__ float pooled[128];
    const int b = blockIdx.x, qt = blockIdx.y, tid = threadIdx.x;
    const f4_t* src =
        (const f4_t*)(features + (size_t)b * CNNC * 49 + qt * (128 * 49));
    f4_t* dst = (f4_t*)raw;
    for (int i = tid; i < 128 * 49 / 4; i += 256)
        dst[i] = __builtin_nontemporal_load(&src[i]);
    __syncthreads();
    if (tid < 128) {
        const float* p = raw + tid * 49;
        float s = 0.f;
        #pragma unroll
        for (int i = 0; i < 49; ++i) s += p[i];
        pooled[tid] = s;
    }
    __syncthreads();
    const int v = tid >> 2, pp = tid & 3;
    if (v < VV) {
        const float* w = W_in + v * CNNC + qt * 128 + pp * 32;
        const float* q = pooled + pp * 32;
        float s = 0.f;
        #pragma unroll
        for (int i = 0; i < 32; ++i) s += q[i] * w[i];
        s += __shfl_xor(s, 1);
        s += __shfl_xor(s, 2);
        if (pp == 0)
            featp[(qt * BB + b) * VV + v] =
                s * (1.f / 49.f) + (qt == 0 ? b_in[v] : 0.f);
    }
}

// ---------------------------------------------------------------------------
// Kernel 2 (FULLY FUSED): xproj-producer + scan + output softmax. 6 waves.
//   wave 0 (tid 0-63):     R2-exact scan (16 lanes/seq, pk dual-FP32 dots,
//                          v_rcp sigmoids). Ring chunk staged LDS->reg at
//                          slot start (16 ds_read_b64, one lgkm wait), then
//                          pure-VALU steps.
//   wave 1 (tid 64-127):   EMIT, one chunk behind scan (R2-proven form).
//   waves 2-5 (tid 128-383): PRODUCER, one chunk ahead: each thread now owns
//                          8 gates (was 16) of one (t, seq) -- ~380-instr
//                          stream vs R7's ~650, so the producer no longer
//                          exceeds the scan chunk and the barrier slot
//                          returns to scan-bound (~6.1K cyc, was 11.3K).
// Ring rows padded to 132 words; producer ds_writes spread across banks.
// Sync: raw s_barrier + lgkmcnt(0) per slot (covers ds_write->ds_read).
// ---------------------------------------------------------------------------
#define TSTR 12                 // hst per-t dword stride (8 data + 4 pad)
#define SSTR (CH * TSTR + 4)    // 196: per (buffer,seq) stride
#define RSTR 132                // ring row stride (128 data + 4 pad)
#define RING_T (CH * RSTR)      // 2112 floats per chunk tile

#define BAR() do {                                                          \
    asm volatile("s_waitcnt lgkmcnt(0)" ::: "memory");                      \
    __builtin_amdgcn_s_barrier();                                           \
    __builtin_amdgcn_sched_barrier(0);                                      \
} while (0)

#define STEP(p2) do {                                                       \
    const float ha0 = h;                                                    \
    const float ha1 = dpp_f<0x4E>(h);                                       \
    const float ha3 = dpp_f<0x141>(h);                                      \
    const float ha2 = dpp_f<0x4E>(ha3);                                     \
    const float ha7 = dpp_f<0x140>(h);                                      \
    const float ha4 = dpp_f<0x141>(ha7);                                    \
    const float ha5 = dpp_f<0x4E>(ha4);                                     \
    const float ha6 = dpp_f<0x1B>(ha7);                                     \
    f2_t acc0 = fma2(w2[0], sp2(ha0), p2);                                  \
    acc0 = fma2(w2[1], sp2(ha1), acc0);                                     \
    acc0 = fma2(w2[2], sp2(ha2), acc0);                                     \
    acc0 = fma2(w2[3], sp2(ha3), acc0);                                     \
    f2_t acc1 = w2[4] * sp2(ha4);                                           \
    acc1 = fma2(w2[5], sp2(ha5), acc1);                                     \
    acc1 = fma2(w2[6], sp2(ha6), acc1);                                     \
    acc1 = fma2(w2[7], sp2(ha7), acc1);                                     \
    const f2_t np2 = acc0 + acc1;                                           \
    const float eA = rcp_f(1.f + exp2_f(np2.x));  /* r=0: i ; r=1: f */     \
    const float uB = rcp_f(1.f + exp2_f(np2.y));  /* r=0: raw g ; r=1: o */ \
    const float gg = fmaf(-4.f * L2E, uB, 2.f * L2E); /* -2L2E*tanh(g) */   \
    const float myU = r ? eA : eA * gg;           /* r=0: -2L2E*i*g; r=1: f */\
    const float otU = dpp_f<0xB1>(myU);                                     \
    const float fg  = r ? myU : otU;                                        \
    const float igg = r ? otU : myU;                                        \
    const float ogx = dpp_f<0xB1>(uB);                                      \
    const float og  = r ? uB : ogx;                                         \
    c = fmaf(fg, c, igg);                         /* c holds -2L2E*c_true */\
    const float rv = rcp_f(1.f + exp2_f(c));                                \
    h = fmaf(og + og, rv, -og);                   /* og*(2rv-1) */          \
} while (0)

#define SCHUNK(it) do {                                                     \
    const float* base = &ring[((it) % 3) * RING_T] + roff2w;                \
    f2_t pbuf[CH];                                                          \
    _Pragma("unroll")                                                       \
    for (int tl = 0; tl < CH; ++tl)                                         \
        pbuf[tl] = *(const f2_t*)&base[tl * RSTR];                          \
    float hsv[CH];                                                          \
    _Pragma("unroll")                                                       \
    for (int tl = 0; tl < CH; ++tl) {                                       \
        STEP(pbuf[tl]);                                                     \
        hsv[tl] = h;                                                        \
    }                                                                       \
    if (r == 0) {                                                           \
        float* hb = &hst[(((it) & 1) * 4 + s4) * SSTR + j];                 \
        _Pragma("unroll")                                                   \
        for (int i = 0; i < CH; ++i) hb[i * TSTR] = hsv[i];                 \
    }                                                                       \
} while (0)

#define PRODUCE_BODY(pk)                                                    \
    float acc[8];                                                           \
    _Pragma("unroll")                                                       \
    for (int g = 0; g < 8; ++g) acc[g] = bs[g];                             \
    _Pragma("unroll")                                                       \
    for (int v = 0; v < VV; ++v) {                                          \
        const float xv = xr[v];                                             \
        _Pragma("unroll")                                                   \
        for (int g = 0; g < 8; ++g) acc[g] += xv * Wih[(g0 + g) * VV + v];  \
    }                                                                       \
    float* dst = &ring[((pk) % 3) * RING_T + ptl * RSTR];                   \
    _Pragma("unroll")                                                       \
    for (int g = 0; g < 8; ++g) {                                           \
        const int gg = g0 + g;                                              \
        const float sc = (gg >= 16 && gg < 24) ? (-2.f * L2E) : (-L2E);     \
        dst[((gg & 15) * 4 + ps) * 2 + (gg >> 4)] = acc[g] * sc;            \
    }

#define PRODUCE(pk) do {          /* pk >= 1: pure caption path */          \
    const int t = (pk) * CH + ptl;                                          \
    const float* x = captions + ((size_t)pb * TT + (t - 1)) * VV;           \
    float xr[VV];                                                           \
    _Pragma("unroll")                                                       \
    for (int v = 0; v < VV; ++v) xr[v] = x[v];                              \
    PRODUCE_BODY(pk)                                                        \
} while (0)

#define EMIT(pk) do {                                                       \
    const int os = lane >> 4, otl = lane & 15;                              \
    const float* hp = &hst[(((pk) & 1) * 4 + os) * SSTR + otl * TSTR];      \
    const f4_t h0 = *(const f4_t*)hp;                                       \
    const f4_t h1 = *(const f4_t*)(hp + 4);                                 \
    const f4_t* W4 = (const f4_t*)Wo;                                       \
    float z[VV];                                                            \
    float m = -1e30f;                                                       \
    _Pragma("unroll")                                                       \
    for (int v = 0; v < VV; ++v) {                                          \
        const f4_t w0 = W4[v * 2], w1 = W4[v * 2 + 1];                      \
        float sv = bo[v];                                                   \
        sv = fmaf(h0.x, w0.x, sv); sv = fmaf(h0.y, w0.y, sv);               \
        sv = fmaf(h0.z, w0.z, sv); sv = fmaf(h0.w, w0.w, sv);               \
        sv = fmaf(h1.x, w1.x, sv); sv = fmaf(h1.y, w1.y, sv);               \
        sv = fmaf(h1.z, w1.z, sv); sv = fmaf(h1.w, w1.w, sv);               \
        z[v] = sv;                                                          \
        m = fmaxf(m, sv);                                                   \
    }                                                                       \
    float sum = 0.f;                                                        \
    _Pragma("unroll")                                                       \
    for (int v = 0; v < VV; ++v) {                                          \
        z[v] = exp2_f((z[v] - m) * L2E);                                    \
        sum += z[v];                                                        \
    }                                                                       \
    const float rs = rcp_f(sum);                                            \
    const int ob = bg * 4 + os;                                             \
    const int ot = (pk) * CH + otl;                                         \
    float* op = out + ((size_t)ob * TT + ot) * VV;                          \
    _Pragma("unroll")                                                       \
    for (int v = 0; v < VV; ++v) op[v] = z[v] * rs;                         \
} while (0)

__global__ __launch_bounds__(384) void k_lstm(const float* __restrict__ W_hh,
                                              const float* __restrict__ captions,
                                              const float* __restrict__ W_ih,
                                              const float* __restrict__ b_ih,
                                              const float* __restrict__ b_hh,
                                              const float* __restrict__ featp,
                                              const float* __restrict__ W_out,
                                              const float* __restrict__ b_out,
                                              float* __restrict__ out) {
    __shared__ __align__(16) float ring[3 * RING_T];    // 25344 B
    __shared__ __align__(16) float hst[2 * 4 * SSTR];   // 6272 B
    __shared__ __align__(16) float Wih[G4 * VV];        // 4736 B
    __shared__ __align__(16) float Wo[VV * HH];         // 1184 B
    __shared__ float bo[VV];

    const int tid  = threadIdx.x;
    const int wv   = tid >> 6;        // 0: scan; 1: emit; 2-5: produce
    const int lane = tid & 63;
    const int bg   = blockIdx.x;      // 0..127 (4-seq groups)

    // scan-wave lane decode
    const int s4 = lane >> 4;
    const int q  = lane & 15;
    const int j  = q >> 1;
    const int r  = q & 1;
    const int rowA   = r * 8 + j;                // i or f row
    const int roff2w = (rowA * 4 + s4) * 2;      // word offset of (A,B) pair

    // producer lane decode (waves 2-5 jointly: p = 0..255)
    const int p   = tid - 128;
    const int ptl = (p >> 4) & 15;     // 0..15 local t
    const int ps  = (p >> 2) & 3;      // seq within block
    const int pq  = p & 3;             // gate quarter (8 gates)
    const int g0  = pq * 8;
    const int pb  = bg * 4 + ps;

    f2_t w2[HH];                       // scan: packed (wA, wB)
    float bs[8];                       // producer: bias registers

    if (wv == 0) {
        const int rowB = 16 + rowA;
        const float scA = -L2E;
        const float scB = r ? -L2E : (-2.f * L2E);
        #pragma unroll
        for (int m = 0; m < HH; ++m) {
            f2_t wp = {scA * W_hh[rowA * HH + (j ^ m)],
                       scB * W_hh[rowB * HH + (j ^ m)]};
            w2[m] = wp;
        }
    } else if (wv == 1) {
        for (int i = lane; i < VV * HH; i += 64) Wo[i] = W_out[i];
        if (lane < VV) bo[lane] = b_out[lane];
    } else {
        for (int i = p; i < G4 * VV; i += 256) Wih[i] = W_ih[i];
        #pragma unroll
        for (int g = 0; g < 8; ++g) bs[g] = b_ih[g0 + g] + b_hh[g0 + g];
    }
    BAR();   // Wih/Wo staged

    // prologue: produce chunk 0 (t=0 row comes from featp partial sums)
    if (wv >= 2) {
        float xr[VV];
        if (ptl == 0) {
            #pragma unroll
            for (int v = 0; v < VV; ++v)
                xr[v] = featp[pb * VV + v] + featp[(BB + pb) * VV + v] +
                        featp[(2 * BB + pb) * VV + v] +
                        featp[(3 * BB + pb) * VV + v];
        } else {
            const float* x = captions + ((size_t)pb * TT + (ptl - 1)) * VV;
            #pragma unroll
            for (int v = 0; v < VV; ++v) xr[v] = x[v];
        }
        PRODUCE_BODY(0)
    }
    BAR();   // chunk 0 ready

    float h = 0.f, c = 0.f;

    // slots 0..16: wave0 scans chunk it (it<16); wave1 emits it-1 (it>=1);
    // waves 2-5 produce chunk it+1 (it<15). Ring: read it%3, write (it+1)%3.
    for (int it = 0; it < NCH + 1; ++it) {
        if (wv == 0) {
            if (it < NCH) SCHUNK(it);
        } else if (wv == 1) {
            if (it >= 1) EMIT(it - 1);
        } else {
            if (it < NCH - 1) PRODUCE(it + 1);
        }
        BAR();
    }
}

// ---------------------------------------------------------------------------
// Workspace (floats): featp@0 (4*512*37=75,776). xproj eliminated.
// ---------------------------------------------------------------------------
extern "C" void kernel_launch(void* const* d_in, const int* in_sizes, int n_in,
                              void* d_out, int out_size, void* d_ws, size_t ws_size,
                              hipStream_t stream) {
    const float* features = (const float*)d_in[0];
    const float* captions = (const float*)d_in[1];
    const float* W_in     = (const float*)d_in[2];
    const float* b_in     = (const float*)d_in[3];
    const float* W_ih     = (const float*)d_in[4];
    const float* W_hh     = (const float*)d_in[5];
    const float* b_ih     = (const float*)d_in[6];
    const float* b_hh     = (const float*)d_in[7];
    const float* W_out    = (const float*)d_in[8];
    const float* b_out    = (const float*)d_in[9];
    float* out = (float*)d_out;

    float* featp = (float*)d_ws;

    k_feat<<<dim3(BB, 4), 256, 0, stream>>>(features, W_in, b_in, featp);
    k_lstm<<<128,         384, 0, stream>>>(W_hh, captions, W_ih, b_ih, b_hh,
                                            featp, W_out, b_out, out);
}

// Round 9
// 163.858 us; speedup vs baseline: 1.2588x; 1.0002x over previous
//
#include <hip/hip_runtime.h>
#include <math.h>

// Problem constants
#define BB   512   // batch
#define TT   256   // timesteps
#define CNNC 512   // channels
#define VV   37    // vocab
#define HH   8     // hidden
#define G4   32    // 4*H
#define CH   16    // scan chunk length (timesteps)
#define NCH  (TT / CH)      // 16 chunks

#define L2E 1.4426950408889634f

// native vector types for vector loads/stores (HIP float4 is a class type)
typedef float f4_t __attribute__((ext_vector_type(4)));
typedef float f2_t __attribute__((ext_vector_type(2)));

// DPP cross-lane mov: pure VALU latency. quad_perm 0xB1=xor1, 0x4E=xor2,
// 0x1B=xor3; 0x141=row_half_mirror (xor7); 0x140=row_mirror (xor15).
template <int CTRL>
__device__ __forceinline__ float dpp_f(float x) {
    int r = __builtin_amdgcn_update_dpp(0, __float_as_int(x), CTRL, 0xF, 0xF, true);
    return __int_as_float(r);
}

__device__ __forceinline__ float rcp_f(float x) { return __builtin_amdgcn_rcpf(x); }
__device__ __forceinline__ float exp2_f(float x) { return __builtin_amdgcn_exp2f(x); }

// packed dual-FP32 helpers (v_pk_fma_f32)
__device__ __forceinline__ f2_t fma2(f2_t a, f2_t b, f2_t c) {
    return __builtin_elementwise_fma(a, b, c);
}
__device__ __forceinline__ f2_t sp2(float x) { f2_t v = {x, x}; return v; }

// ---------------------------------------------------------------------------
// Kernel 1: avg-pool(features) @ W_in.T partial -> featp[quarter][B][V]
// (unchanged: BW-bound on the 51 MB feature read, at roofline)
// ---------------------------------------------------------------------------
__global__ __launch_bounds__(256) void k_feat(const float* __restrict__ features,
                                              const float* __restrict__ W_in,
                                              const float* __restrict__ b_in,
                                              float* __restrict__ featp) {
    __shared__ __align__(16) float raw[128 * 49];    // 25088 B
    __shared__ float pooled[128];
    const int b = blockIdx.x, qt = blockIdx.y, tid = threadIdx.x;
    const f4_t* src =
        (const f4_t*)(features + (size_t)b * CNNC * 49 + qt * (128 * 49));
    f4_t* dst = (f4_t*)raw;
    for (int i = tid; i < 128 * 49 / 4; i += 256)
        dst[i] = __builtin_nontemporal_load(&src[i]);
    __syncthreads();
    if (tid < 128) {
        const float* p = raw + tid * 49;
        float s = 0.f;
        #pragma unroll
        for (int i = 0; i < 49; ++i) s += p[i];
        pooled[tid] = s;
    }
    __syncthreads();
    const int v = tid >> 2, pp = tid & 3;
    if (v < VV) {
        const float* w = W_in + v * CNNC + qt * 128 + pp * 32;
        const float* q = pooled + pp * 32;
        float s = 0.f;
        #pragma unroll
        for (int i = 0; i < 32; ++i) s += q[i] * w[i];
        s += __shfl_xor(s, 1);
        s += __shfl_xor(s, 2);
        if (pp == 0)
            featp[(qt * BB + b) * VV + v] =
                s * (1.f / 49.f) + (qt == 0 ? b_in[v] : 0.f);
    }
}

// ---------------------------------------------------------------------------
// Kernel 2 (FULLY FUSED): xproj-producer + scan + output softmax. 6 waves.
//   wave 0 (tid 0-63):     R2-exact scan. NEW: producers run TWO chunks
//                          ahead, so chunk it+1 is complete when slot it
//                          begins -- the scan issues its 16 ds_read_b64 for
//                          it+1 at slot START (pinned), computes chunk it
//                          from registers, and the reads retire under the
//                          ~5.7K-cyc compute. The slot-start LDS wait leaves
//                          the critical path. Ring = depth-2 (parity),
//                          register double-buffer cA/cB (static indexing).
//   wave 1 (tid 64-127):   EMIT, one chunk behind scan (R8 form).
//   waves 2-5 (tid 128-383): PRODUCER, two chunks ahead, 8 gates/thread.
// Sync: raw s_barrier + lgkmcnt(0) per slot (covers ds_write->ds_read and
// confirms the scan's prefetch reads landed before the next slot).
// ---------------------------------------------------------------------------
#define TSTR 12                 // hst per-t dword stride (8 data + 4 pad)
#define SSTR (CH * TSTR + 4)    // 196: per (buffer,seq) stride
#define RSTR 132                // ring row stride (128 data + 4 pad)
#define RING_T (CH * RSTR)      // 2112 floats per chunk tile

#define BAR() do {                                                          \
    asm volatile("s_waitcnt lgkmcnt(0)" ::: "memory");                      \
    __builtin_amdgcn_s_barrier();                                           \
    __builtin_amdgcn_sched_barrier(0);                                      \
} while (0)

#define STEP(p2) do {                                                       \
    const float ha0 = h;                                                    \
    const float ha1 = dpp_f<0x4E>(h);                                       \
    const float ha3 = dpp_f<0x141>(h);                                      \
    const float ha2 = dpp_f<0x4E>(ha3);                                     \
    const float ha7 = dpp_f<0x140>(h);                                      \
    const float ha4 = dpp_f<0x141>(ha7);                                    \
    const float ha5 = dpp_f<0x4E>(ha4);                                     \
    const float ha6 = dpp_f<0x1B>(ha7);                                     \
    f2_t acc0 = fma2(w2[0], sp2(ha0), p2);                                  \
    acc0 = fma2(w2[1], sp2(ha1), acc0);                                     \
    acc0 = fma2(w2[2], sp2(ha2), acc0);                                     \
    acc0 = fma2(w2[3], sp2(ha3), acc0);                                     \
    f2_t acc1 = w2[4] * sp2(ha4);                                           \
    acc1 = fma2(w2[5], sp2(ha5), acc1);                                     \
    acc1 = fma2(w2[6], sp2(ha6), acc1);                                     \
    acc1 = fma2(w2[7], sp2(ha7), acc1);                                     \
    const f2_t np2 = acc0 + acc1;                                           \
    const float eA = rcp_f(1.f + exp2_f(np2.x));  /* r=0: i ; r=1: f */     \
    const float uB = rcp_f(1.f + exp2_f(np2.y));  /* r=0: raw g ; r=1: o */ \
    const float gg = fmaf(-4.f * L2E, uB, 2.f * L2E); /* -2L2E*tanh(g) */   \
    const float myU = r ? eA : eA * gg;           /* r=0: -2L2E*i*g; r=1: f */\
    const float otU = dpp_f<0xB1>(myU);                                     \
    const float fg  = r ? myU : otU;                                        \
    const float igg = r ? otU : myU;                                        \
    const float ogx = dpp_f<0xB1>(uB);                                      \
    const float og  = r ? uB : ogx;                                         \
    c = fmaf(fg, c, igg);                         /* c holds -2L2E*c_true */\
    const float rv = rcp_f(1.f + exp2_f(c));                                \
    h = fmaf(og + og, rv, -og);                   /* og*(2rv-1) */          \
} while (0)

// issue prefetch of chunk (into reg buffer `dst`) from ring parity `par`
#define PREF(dst, par) do {                                                 \
    const float* base = &ring[(par) * RING_T] + roff2w;                     \
    _Pragma("unroll")                                                       \
    for (int tl = 0; tl < CH; ++tl)                                         \
        dst[tl] = *(const f2_t*)&base[tl * RSTR];                           \
} while (0)

// compute chunk `it` from register buffer `cur`; flush h to hst[it&1]
#define SCHUNK(cur, it) do {                                                \
    float hsv[CH];                                                          \
    _Pragma("unroll")                                                       \
    for (int tl = 0; tl < CH; ++tl) {                                       \
        STEP(cur[tl]);                                                      \
        hsv[tl] = h;                                                        \
    }                                                                       \
    if (r == 0) {                                                           \
        float* hb = &hst[(((it) & 1) * 4 + s4) * SSTR + j];                 \
        _Pragma("unroll")                                                   \
        for (int i = 0; i < CH; ++i) hb[i * TSTR] = hsv[i];                 \
    }                                                                       \
} while (0)

#define PRODUCE_BODY(par)                                                   \
    float acc[8];                                                           \
    _Pragma("unroll")                                                       \
    for (int g = 0; g < 8; ++g) acc[g] = bs[g];                             \
    _Pragma("unroll")                                                       \
    for (int v = 0; v < VV; ++v) {                                          \
        const float xv = xr[v];                                             \
        _Pragma("unroll")                                                   \
        for (int g = 0; g < 8; ++g) acc[g] += xv * Wih[(g0 + g) * VV + v];  \
    }                                                                       \
    float* dst = &ring[(par) * RING_T + ptl * RSTR];                        \
    _Pragma("unroll")                                                       \
    for (int g = 0; g < 8; ++g) {                                           \
        const int gg = g0 + g;                                              \
        const float sc = (gg >= 16 && gg < 24) ? (-2.f * L2E) : (-L2E);     \
        dst[((gg & 15) * 4 + ps) * 2 + (gg >> 4)] = acc[g] * sc;            \
    }

#define PRODUCE(pk, par) do {     /* pk >= 1: pure caption path */          \
    const int t = (pk) * CH + ptl;                                          \
    const float* x = captions + ((size_t)pb * TT + (t - 1)) * VV;           \
    float xr[VV];                                                           \
    _Pragma("unroll")                                                       \
    for (int v = 0; v < VV; ++v) xr[v] = x[v];                              \
    PRODUCE_BODY(par)                                                       \
} while (0)

#define EMIT(pk) do {                                                       \
    const int os = lane >> 4, otl = lane & 15;                              \
    const float* hp = &hst[(((pk) & 1) * 4 + os) * SSTR + otl * TSTR];      \
    const f4_t h0 = *(const f4_t*)hp;                                       \
    const f4_t h1 = *(const f4_t*)(hp + 4);                                 \
    const f4_t* W4 = (const f4_t*)Wo;                                       \
    float z[VV];                                                            \
    float m = -1e30f;                                                       \
    _Pragma("unroll")                                                       \
    for (int v = 0; v < VV; ++v) {                                          \
        const f4_t w0 = W4[v * 2], w1 = W4[v * 2 + 1];                      \
        float sv = bo[v];                                                   \
        sv = fmaf(h0.x, w0.x, sv); sv = fmaf(h0.y, w0.y, sv);               \
        sv = fmaf(h0.z, w0.z, sv); sv = fmaf(h0.w, w0.w, sv);               \
        sv = fmaf(h1.x, w1.x, sv); sv = fmaf(h1.y, w1.y, sv);               \
        sv = fmaf(h1.z, w1.z, sv); sv = fmaf(h1.w, w1.w, sv);               \
        z[v] = sv;                                                          \
        m = fmaxf(m, sv);                                                   \
    }                                                                       \
    float sum = 0.f;                                                        \
    _Pragma("unroll")                                                       \
    for (int v = 0; v < VV; ++v) {                                          \
        z[v] = exp2_f((z[v] - m) * L2E);                                    \
        sum += z[v];                                                        \
    }                                                                       \
    const float rs = rcp_f(sum);                                            \
    const int ob = bg * 4 + os;                                             \
    const int ot = (pk) * CH + otl;                                         \
    float* op = out + ((size_t)ob * TT + ot) * VV;                          \
    _Pragma("unroll")                                                       \
    for (int v = 0; v < VV; ++v) op[v] = z[v] * rs;                         \
} while (0)

__global__ __launch_bounds__(384) void k_lstm(const float* __restrict__ W_hh,
                                              const float* __restrict__ captions,
                                              const float* __restrict__ W_ih,
                                              const float* __restrict__ b_ih,
                                              const float* __restrict__ b_hh,
                                              const float* __restrict__ featp,
                                              const float* __restrict__ W_out,
                                              const float* __restrict__ b_out,
                                              float* __restrict__ out) {
    __shared__ __align__(16) float ring[2 * RING_T];    // 16896 B
    __shared__ __align__(16) float hst[2 * 4 * SSTR];   // 6272 B
    __shared__ __align__(16) float Wih[G4 * VV];        // 4736 B
    __shared__ __align__(16) float Wo[VV * HH];         // 1184 B
    __shared__ float bo[VV];

    const int tid  = threadIdx.x;
    const int wv   = tid >> 6;        // 0: scan; 1: emit; 2-5: produce
    const int lane = tid & 63;
    const int bg   = blockIdx.x;      // 0..127 (4-seq groups)

    // scan-wave lane decode
    const int s4 = lane >> 4;
    const int q  = lane & 15;
    const int j  = q >> 1;
    const int r  = q & 1;
    const int rowA   = r * 8 + j;                // i or f row
    const int roff2w = (rowA * 4 + s4) * 2;      // word offset of (A,B) pair

    // producer lane decode (waves 2-5 jointly: p = 0..255)
    const int p   = tid - 128;
    const int ptl = (p >> 4) & 15;     // 0..15 local t
    const int ps  = (p >> 2) & 3;      // seq within block
    const int pq  = p & 3;             // gate quarter (8 gates)
    const int g0  = pq * 8;
    const int pb  = bg * 4 + ps;

    f2_t w2[HH];                       // scan: packed (wA, wB)
    f2_t cA[CH], cB[CH];               // scan: register chunk double-buffer
    float bs[8];                       // producer: bias registers

    if (wv == 0) {
        const int rowB = 16 + rowA;
        const float scA = -L2E;
        const float scB = r ? -L2E : (-2.f * L2E);
        #pragma unroll
        for (int m = 0; m < HH; ++m) {
            f2_t wp = {scA * W_hh[rowA * HH + (j ^ m)],
                       scB * W_hh[rowB * HH + (j ^ m)]};
            w2[m] = wp;
        }
    } else if (wv == 1) {
        for (int i = lane; i < VV * HH; i += 64) Wo[i] = W_out[i];
        if (lane < VV) bo[lane] = b_out[lane];
    } else {
        for (int i = p; i < G4 * VV; i += 256) Wih[i] = W_ih[i];
        #pragma unroll
        for (int g = 0; g < 8; ++g) bs[g] = b_ih[g0 + g] + b_hh[g0 + g];
    }
    BAR();   // Wih/Wo staged

    // prologue A: produce chunk 0 -> ring parity 0 (t=0 row from featp)
    if (wv >= 2) {
        float xr[VV];
        if (ptl == 0) {
            #pragma unroll
            for (int v = 0; v < VV; ++v)
                xr[v] = featp[pb * VV + v] + featp[(BB + pb) * VV + v] +
                        featp[(2 * BB + pb) * VV + v] +
                        featp[(3 * BB + pb) * VV + v];
        } else {
            const float* x = captions + ((size_t)pb * TT + (ptl - 1)) * VV;
            #pragma unroll
            for (int v = 0; v < VV; ++v) xr[v] = x[v];
        }
        PRODUCE_BODY(0)
    }
    BAR();   // chunk 0 ready

    // prologue B: produce chunk 1 -> parity 1; scan prefetches chunk 0 -> cA
    if (wv == 0) {
        PREF(cA, 0);
    } else if (wv >= 2) {
        PRODUCE(1, 1);
    }
    BAR();   // chunk 1 ready, cA loaded

    float h = 0.f, c = 0.f;

    // slots it=0..16: scan computes chunk it from regs + prefetches it+1;
    // emit outputs it-1; producers build it+2 (two ahead). Parity static
    // via unroll-by-2 (rule #20: no runtime-indexed register arrays).
    for (int ou = 0; ou < 9; ++ou) {
        {   // even slot: it = 2*ou. chunk it+1 is in parity 1; produce->par 0.
            const int it = ou * 2;
            if (wv == 0) {
                if (it < NCH) {
                    if (it + 1 < NCH) PREF(cB, 1);
                    __builtin_amdgcn_sched_barrier(0);
                    SCHUNK(cA, it);
                }
            } else if (wv == 1) {
                if (it >= 1) EMIT(it - 1);
            } else {
                if (it + 2 < NCH) PRODUCE(it + 2, 0);
            }
            BAR();
        }
        {   // odd slot: it = 2*ou+1. chunk it+1 in parity 0; produce->par 1.
            const int it = ou * 2 + 1;
            if (it <= NCH) {
                if (wv == 0) {
                    if (it < NCH) {
                        PREF(cA, 0);
                        __builtin_amdgcn_sched_barrier(0);
                        SCHUNK(cB, it);
                    }
                } else if (wv == 1) {
                    EMIT(it - 1);
                } else {
                    if (it + 2 < NCH) PRODUCE(it + 2, 1);
                }
                BAR();
            }
        }
    }
}

// ---------------------------------------------------------------------------
// Workspace (floats): featp@0 (4*512*37=75,776). xproj eliminated.
// ---------------------------------------------------------------------------
extern "C" void kernel_launch(void* const* d_in, const int* in_sizes, int n_in,
                              void* d_out, int out_size, void* d_ws, size_t ws_size,
                              hipStream_t stream) {
    const float* features = (const float*)d_in[0];
    const float* captions = (const float*)d_in[1];
    const float* W_in     = (const float*)d_in[2];
    const float* b_in     = (const float*)d_in[3];
    const float* W_ih     = (const float*)d_in[4];
    const float* W_hh     = (const float*)d_in[5];
    const float* b_ih     = (const float*)d_in[6];
    const float* b_hh     = (const float*)d_in[7];
    const float* W_out    = (const float*)d_in[8];
    const float* b_out    = (const float*)d_in[9];
    float* out = (float*)d_out;

    float* featp = (float*)d_ws;

    k_feat<<<dim3(BB, 4), 256, 0, stream>>>(features, W_in, b_in, featp);
    k_lstm<<<128,         384, 0, stream>>>(W_hh, captions, W_ih, b_ih, b_hh,
                                            featp, W_out, b_out, out);
}